// Round 3
// baseline (205.316 us; speedup 1.0000x reference)
//
#include <hip/hip_runtime.h>

// Problem constants (match reference setup_inputs).
#define BB 4
#define CC 128
#define CE 64
#define VV 4096
#define NLEV 14   // MAX_LEVELS

// Workspace layout (A = BB*VV*4 = 64 KB):
//   wsort  ws+0        [BB*VV] f32   edge weight at SORTED position i (K2 tree blocks, agent-scope)
//   giInv  ws+A        [BB*VV] i32   pixel v -> levelpos k
//   cpl    ws+2A       [BB*VV] int2  {cp, sorted idx i} at levelpos k
//   offs   ws+4A       [BB*16] i32   level start offsets
//   sync   ws+4A+4096  [8] i32       done[4] (weight counters), flag2[4] (nrm ready)
//   nrmInv ws+5A       [BB*VV] f32   1/nrm by levelpos (K2 leader blocks)
//   embedT ws+6A       [BB*VV*CE]    transposed embed [b][v][ce] (K1)

__device__ __forceinline__ void lds_fadd(float* p, float v) {
    unsafeAtomicAdd(p, v);   // ds_add_f32 on gfx950 LDS
}
__device__ __forceinline__ float agent_loadf(const float* p) {
    return __hip_atomic_load(p, __ATOMIC_RELAXED, __HIP_MEMORY_SCOPE_AGENT);
}
__device__ __forceinline__ void agent_storef(float* p, float v) {
    __hip_atomic_store(p, v, __ATOMIC_RELAXED, __HIP_MEMORY_SCOPE_AGENT);
}
__device__ __forceinline__ int agent_loadi(const int* p) {
    return __hip_atomic_load(p, __ATOMIC_RELAXED, __HIP_MEMORY_SCOPE_AGENT);
}

// ---------------------------------------------------------------------------
// K1: blocks [0,BB)      : per-batch counting sort -> tables (+ zero sync flags)
//     blocks [BB,BB+256) : tile-transpose embed [ce][v] -> embedT [v][ce]
// Weight moved into K2 (reads embedT with contiguous 256B rows instead of
// 2.1M single-line 4B gathers: ~134 MB line traffic -> ~8 MB).
// ---------------------------------------------------------------------------
__global__ __launch_bounds__(256) void prep_kernel(
    const float* __restrict__ embed,
    const int* __restrict__ sorted_index,
    const int* __restrict__ sorted_parent,
    const int* __restrict__ node_level,
    int*   __restrict__ giInv,
    int2*  __restrict__ cpl,
    int*   __restrict__ offs,
    int*   __restrict__ sync,
    float* __restrict__ embedT)
{
    int tid = threadIdx.x;
    if (blockIdx.x < BB) {
        int b = blockIdx.x;
        if (tid == 0) { sync[b] = 0; sync[4 + b] = 0; }   // re-zero each iteration
        __shared__ int  pos_s[VV];            // 16 KB: i -> levelpos k
        __shared__ int4 cntv[NLEV * 64];      // 14 KB: [level][thread] counts/offsets
        __shared__ int  tot[NLEV];
        __shared__ int  offSh[NLEV + 1];
        int* cnt = (int*)cntv;
        const int* lev = node_level    + b * VV;
        const int* si  = sorted_index  + b * VV;
        const int* par = sorted_parent + b * VV;
        int lane = tid & 63;
        int w    = tid >> 6;

        // ---- load: thread owns elements i = 16*tid + m
        int dreg[16], sreg[16];
        #pragma unroll
        for (int t = 0; t < 4; ++t) {
            int4 dv = ((const int4*)lev)[tid * 4 + t];
            int4 sv = ((const int4*)si)[tid * 4 + t];
            #pragma unroll
            for (int j = 0; j < 4; ++j) {
                int d = (&dv.x)[j]; d = d < NLEV - 1 ? d : NLEV - 1;
                dreg[t * 4 + j] = d;
                sreg[t * 4 + j] = (&sv.x)[j];
            }
        }
        // ---- in-thread rank
        int rank[16];
        #pragma unroll
        for (int m = 0; m < 16; ++m) {
            int r = 0;
            #pragma unroll
            for (int m2 = 0; m2 < m; ++m2) r += (dreg[m2] == dreg[m]) ? 1 : 0;
            rank[m] = r;
        }
        // ---- per-thread per-level counts
        #pragma unroll
        for (int d = 0; d < NLEV; ++d) {
            int c = 0;
            #pragma unroll
            for (int m = 0; m < 16; ++m) c += (dreg[m] == d) ? 1 : 0;
            cnt[d * 256 + tid] = c;
        }
        __syncthreads();
        // ---- exclusive scan per level; wave w does levels w, w+4, ...
        for (int d = w; d < NLEV; d += 4) {
            int base = d * 64 + lane;
            int4 cv = cntv[base];
            int ls = cv.x + cv.y + cv.z + cv.w;
            int x = ls;
            #pragma unroll
            for (int off = 1; off < 64; off <<= 1) {
                int y = __shfl_up(x, off, 64);
                if (lane >= off) x += y;
            }
            int excl = x - ls;
            int4 ov;
            ov.x = excl;
            ov.y = excl + cv.x;
            ov.z = excl + cv.x + cv.y;
            ov.w = excl + cv.x + cv.y + cv.z;
            cntv[base] = ov;
            if (lane == 63) tot[d] = x;
        }
        __syncthreads();
        if (tid == 0) {
            int acc = 0;
            for (int d = 0; d < NLEV; ++d) { offSh[d] = acc; acc += tot[d]; }
            offSh[NLEV] = acc;
        }
        __syncthreads();
        if (tid <= NLEV) offs[b * 16 + tid] = offSh[tid];
        // ---- rank assignment
        int kreg[16];
        #pragma unroll
        for (int m = 0; m < 16; ++m) {
            int d = dreg[m];
            int k = offSh[d] + cnt[d * 256 + tid] + rank[m];
            kreg[m] = k;
            pos_s[16 * tid + m] = k;
            giInv[b * VV + sreg[m]] = k;
        }
        __syncthreads();
        // ---- emit cpl
        #pragma unroll
        for (int t = 0; t < 4; ++t) {
            int4 pv = ((const int4*)par)[tid * 4 + t];
            #pragma unroll
            for (int j = 0; j < 4; ++j) {
                int m = t * 4 + j;
                int p = (&pv.x)[j];
                cpl[b * VV + kreg[m]] = make_int2(pos_s[p], 16 * tid + m);
            }
        }
    } else {
        // ---- transpose: block handles batch b, v-range [v0, v0+64)
        __shared__ float tile[64][65];
        int tb = blockIdx.x - BB;
        int b  = tb >> 6;
        int v0 = (tb & 63) << 6;
        const float* eb  = embed  + (size_t)b * CE * VV;
        float*       ebT = embedT + (size_t)b * VV * CE;
        int cv = tid & 63;          // lane -> contiguous dim
        int rh = tid >> 6;          // 4 rows per iteration
        #pragma unroll
        for (int it = 0; it < 16; ++it) {
            int ce = it * 4 + rh;
            tile[cv][ce] = eb[(size_t)ce * VV + v0 + cv];   // coalesced read
        }
        __syncthreads();
        #pragma unroll
        for (int it = 0; it < 16; ++it) {
            int dv = it * 4 + rh;
            ebT[(size_t)(v0 + dv) * CE + cv] = tile[dv][cv]; // coalesced write
        }
    }
}

// ---------------------------------------------------------------------------
// K2 (fused weight + nrm-hoist + tree). Grid 260 x 512 threads, 48 KB LDS,
// __launch_bounds__(512,4) -> >=2 blocks/CU -> all 260 blocks co-resident
// (capacity: LDS 160/48=3, waves 16<=32, VGPR<=128) => spin-waits safe.
//   blocks 0..3    : leaders. Spin for weights, compute the SHARED nrm chain
//                    once per batch, publish nrmInv (was computed 64x/batch).
//   blocks 4..259  : (a) weight for their 64-node group from embedT (float4,
//                    8 lanes/node, shfl reduce), publish + bump done[b];
//                    (b) prefetch feat/giInv to regs, pre-pack cpl;
//                    (c) spin done[b]==64; stage wsort coalesced->LDS, pack
//                    cw={w_hi20,cp12}; (d) val-only up/down (2 atomics/node,
//                    -33% vs 3); (e) spin flag2[b], stage nrmInv, epilogue.
// val & nrm use the SAME truncated w so the division cancels perturbation.
// ---------------------------------------------------------------------------
__global__ __launch_bounds__(512, 4) void tree2_kernel(
    const float* __restrict__ feat,
    const float* __restrict__ embedT,
    const int*  __restrict__ sorted_index,
    const int*  __restrict__ sorted_parent,
    float* __restrict__ wsort,
    const int*  __restrict__ giInv,
    const int2* __restrict__ cpl,
    const int*  __restrict__ offs,
    int*   __restrict__ sync,
    float* __restrict__ nrmInv,
    float* __restrict__ out)
{
    __shared__ float val0[VV];   // 16 KB (leaders: wsort stage / nrm chain)
    __shared__ float val1[VV];   // 16 KB
    __shared__ int   cw[VV];     // 16 KB packed {w_hi20, cp12}
    __shared__ int   offS[16];
    int tid = threadIdx.x;

    if (blockIdx.x < BB) {
        // ================= leader: shared nrm chain for batch b =============
        int b = blockIdx.x;
        const int2* cplB = cpl + b * VV;
        if (tid < 16) offS[tid] = offs[b * 16 + tid];
        #pragma unroll
        for (int t = 0; t < 8; ++t) {
            int k = tid + t * 512;
            int2 x = cplB[k];
            cw[k] = x.x | (x.y << 12);          // pre-pack {iy, cp}
        }
        if (tid == 0) {
            while (agent_loadi(&sync[b]) < 64) __builtin_amdgcn_s_sleep(1);
        }
        __syncthreads();
        __threadfence();
        // stage wsort coalesced -> val0 (indexed by i), then pack
        #pragma unroll
        for (int t = 0; t < 8; ++t) {
            int k = tid + t * 512;
            val0[k] = agent_loadf(&wsort[b * VV + k]);
        }
        __syncthreads();
        #pragma unroll
        for (int t = 0; t < 8; ++t) {
            int k = tid + t * 512;
            int pk = cw[k];
            int iy = (pk >> 12) & 0xFFF;
            int wb = __float_as_int(val0[iy]);
            cw[k] = (wb & 0xFFFFF000) | (pk & 0xFFF);
        }
        __syncthreads();
        #pragma unroll
        for (int t = 0; t < 8; ++t) val0[tid + t * 512] = 1.f;   // nrm init
        __syncthreads();
        for (int d = NLEV - 1; d >= 1; --d) {
            int s = offS[d], e = offS[d + 1];
            if (s == e) continue;
            for (int k = s + tid; k < e; k += 512) {
                int x = cw[k];
                float w = __int_as_float(x & 0xFFFFF000);
                int  cp = x & 0xFFF;
                lds_fadd(&val0[cp], w * val0[k]);
            }
            __syncthreads();
        }
        for (int d = 1; d <= NLEV - 1; ++d) {
            int s = offS[d], e = offS[d + 1];
            if (s == e) continue;
            for (int k = s + tid; k < e; k += 512) {
                int x = cw[k];
                float w = __int_as_float(x & 0xFFFFF000);
                int  cp = x & 0xFFF;
                float un = val0[k];
                val0[k] = fmaf(w, fmaf(-w, un, val0[cp]), un);
            }
            __syncthreads();
        }
        #pragma unroll
        for (int t = 0; t < 8; ++t) {
            int k = tid + t * 512;
            agent_storef(&nrmInv[b * VV + k], __fdividef(1.f, val0[k]));
        }
        __threadfence();
        __syncthreads();
        if (tid == 0) __hip_atomic_store(&sync[4 + b], 1, __ATOMIC_RELAXED, __HIP_MEMORY_SCOPE_AGENT);
        return;
    }

    // ==================== tree block: 2 channels ============================
    int tb = blockIdx.x - BB;
    int b  = tb >> 6;
    int j  = tb & 63;
    int c0 = j << 1;

    const int2*  cplB = cpl   + b * VV;
    const int*   ivB  = giInv + b * VV;
    const float* f0   = feat + ((size_t)(b * CC + c0)) * VV;
    const float* f1   = f0 + VV;

    // ---- (a) weight for node group [64j, 64j+64): 8 lanes per node
    {
        int n   = tid >> 3;
        int sub = tid & 7;
        int i   = (j << 6) + n;
        int vi = sorted_index[b * VV + i];
        int p  = sorted_parent[b * VV + i];
        int vp = sorted_index[b * VV + p];
        const float4* ra = (const float4*)(embedT + ((size_t)b * VV + vi) * CE);
        const float4* rb = (const float4*)(embedT + ((size_t)b * VV + vp) * CE);
        float4 a0 = ra[sub * 2], a1 = ra[sub * 2 + 1];
        float4 b0 = rb[sub * 2], b1 = rb[sub * 2 + 1];
        float d2 = 0.f, t0;
        t0 = a0.x - b0.x; d2 = fmaf(t0, t0, d2);
        t0 = a0.y - b0.y; d2 = fmaf(t0, t0, d2);
        t0 = a0.z - b0.z; d2 = fmaf(t0, t0, d2);
        t0 = a0.w - b0.w; d2 = fmaf(t0, t0, d2);
        t0 = a1.x - b1.x; d2 = fmaf(t0, t0, d2);
        t0 = a1.y - b1.y; d2 = fmaf(t0, t0, d2);
        t0 = a1.z - b1.z; d2 = fmaf(t0, t0, d2);
        t0 = a1.w - b1.w; d2 = fmaf(t0, t0, d2);
        d2 += __shfl_xor(d2, 1, 64);
        d2 += __shfl_xor(d2, 2, 64);
        d2 += __shfl_xor(d2, 4, 64);
        if (sub == 0) agent_storef(&wsort[b * VV + i], __expf(-d2));
    }
    __threadfence();
    __syncthreads();
    if (tid == 0) __hip_atomic_fetch_add(&sync[b], 1, __ATOMIC_RELAXED, __HIP_MEMORY_SCOPE_AGENT);

    // ---- (b) overlap with spin: prefetch feat/giInv to regs, pre-pack cpl
    if (tid < 16) offS[tid] = offs[b * 16 + tid];
    int4   kkR[2];
    float4 fA[2], fB[2];
    #pragma unroll
    for (int t = 0; t < 2; ++t) {
        int idx = tid + t * 512;
        kkR[t] = ((const int4*)ivB)[idx];
        fA[t]  = ((const float4*)f0)[idx];
        fB[t]  = ((const float4*)f1)[idx];
    }
    #pragma unroll
    for (int t = 0; t < 8; ++t) {
        int k = tid + t * 512;
        int2 x = cplB[k];
        cw[k] = x.x | (x.y << 12);
    }

    // ---- (c) spin for weights; stage wsort coalesced -> val0; pack cw
    if (tid == 0) {
        while (agent_loadi(&sync[b]) < 64) __builtin_amdgcn_s_sleep(1);
    }
    __syncthreads();
    __threadfence();
    #pragma unroll
    for (int t = 0; t < 8; ++t) {
        int k = tid + t * 512;
        val0[k] = agent_loadf(&wsort[b * VV + k]);
    }
    __syncthreads();
    #pragma unroll
    for (int t = 0; t < 8; ++t) {
        int k = tid + t * 512;
        int pk = cw[k];
        int iy = (pk >> 12) & 0xFFF;
        int wb = __float_as_int(val0[iy]);
        cw[k] = (wb & 0xFFFFF000) | (pk & 0xFFF);
    }
    __syncthreads();
    // scatter prefetched feat into val0/val1 by levelpos
    #pragma unroll
    for (int t = 0; t < 2; ++t) {
        int4 kk = kkR[t];
        val0[kk.x] = fA[t].x; val0[kk.y] = fA[t].y; val0[kk.z] = fA[t].z; val0[kk.w] = fA[t].w;
        val1[kk.x] = fB[t].x; val1[kk.y] = fB[t].y; val1[kk.z] = fB[t].z; val1[kk.w] = fB[t].w;
    }
    __syncthreads();

    // ---- (d) upward: 2 atomics/node (nrm hoisted to leaders)
    for (int d = NLEV - 1; d >= 1; --d) {
        int s = offS[d], e = offS[d + 1];
        if (s == e) continue;
        for (int k = s + tid; k < e; k += 512) {
            int x = cw[k];
            float w = __int_as_float(x & 0xFFFFF000);
            int  cp = x & 0xFFF;
            lds_fadd(&val0[cp], w * val0[k]);
            lds_fadd(&val1[cp], w * val1[k]);
        }
        __syncthreads();
    }
    // downward
    for (int d = 1; d <= NLEV - 1; ++d) {
        int s = offS[d], e = offS[d + 1];
        if (s == e) continue;
        for (int k = s + tid; k < e; k += 512) {
            int x = cw[k];
            float w = __int_as_float(x & 0xFFFFF000);
            int  cp = x & 0xFFF;
            float u0 = val0[k], u1 = val1[k];
            val0[k] = fmaf(w, fmaf(-w, u0, val0[cp]), u0);
            val1[k] = fmaf(w, fmaf(-w, u1, val1[cp]), u1);
        }
        __syncthreads();
    }

    // ---- (e) nrmInv: spin leaders, stage coalesced into cw (dead), epilogue
    if (tid == 0) {
        while (agent_loadi(&sync[4 + b]) == 0) __builtin_amdgcn_s_sleep(1);
    }
    __syncthreads();
    __threadfence();
    float* nv = (float*)cw;
    #pragma unroll
    for (int t = 0; t < 8; ++t) {
        int k = tid + t * 512;
        nv[k] = agent_loadf(&nrmInv[b * VV + k]);
    }
    __syncthreads();

    float* o0 = out + ((size_t)(b * CC + c0)) * VV;
    float* o1 = o0 + VV;
    #pragma unroll
    for (int t = 0; t < 2; ++t) {
        int idx = tid + t * 512;
        int4 kk = kkR[t];
        float i0 = nv[kk.x], i1 = nv[kk.y], i2 = nv[kk.z], i3 = nv[kk.w];
        float4 r0, r1;
        r0.x = val0[kk.x] * i0; r0.y = val0[kk.y] * i1;
        r0.z = val0[kk.z] * i2; r0.w = val0[kk.w] * i3;
        r1.x = val1[kk.x] * i0; r1.y = val1[kk.y] * i1;
        r1.z = val1[kk.z] * i2; r1.w = val1[kk.w] * i3;
        ((float4*)o0)[idx] = r0;
        ((float4*)o1)[idx] = r1;
    }
}

extern "C" void kernel_launch(void* const* d_in, const int* in_sizes, int n_in,
                              void* d_out, int out_size, void* d_ws, size_t ws_size,
                              hipStream_t stream) {
    const float* feat          = (const float*)d_in[0];
    const float* embed         = (const float*)d_in[1];
    const int*   sorted_index  = (const int*)d_in[2];
    const int*   sorted_parent = (const int*)d_in[3];
    const int*   node_level    = (const int*)d_in[4];
    float* out = (float*)d_out;

    char* ws = (char*)d_ws;
    const size_t A = (size_t)BB * VV * 4;          // 64 KB
    float* wsort  = (float*)(ws);                  // 64 KB
    int*   giInv  = (int*)  (ws + A);              // 64 KB
    int2*  cpl    = (int2*) (ws + 2 * A);          // 128 KB
    int*   offs   = (int*)  (ws + 4 * A);          // 256 B
    int*   sync   = (int*)  (ws + 4 * A + 4096);   // 32 B
    float* nrmInv = (float*)(ws + 5 * A);          // 64 KB
    float* embedT = (float*)(ws + 6 * A);          // 4 MB

    prep_kernel<<<BB + 256, 256, 0, stream>>>(
        embed, sorted_index, sorted_parent, node_level, giInv, cpl, offs, sync, embedT);

    tree2_kernel<<<BB + 256, 512, 0, stream>>>(
        feat, embedT, sorted_index, sorted_parent, wsort, giInv, cpl, offs, sync, nrmInv, out);
}

// Round 4
// 111.073 us; speedup vs baseline: 1.8485x; 1.8485x over previous
//
#include <hip/hip_runtime.h>

// Problem constants (match reference setup_inputs).
#define BB 4
#define CC 128
#define CE 64
#define VV 4096
#define NLEV 14   // MAX_LEVELS

// Workspace (r2 layout):
//   wsort [BB*VV] float : edge weight of node at SORTED position i
//   giInv [BB*VV] int   : levelpos of pixel v
//   cpl   [BB*VV] int2  : {cp (levelpos of parent), sorted idx i} at levelpos k
//   offs  [BB*16] int   : level start offsets

__device__ __forceinline__ void lds_fadd(float* p, float v) {
    unsafeAtomicAdd(p, v);   // ds_add_f32 on gfx950 LDS
}

// ---------------------------------------------------------------------------
// K1 (fused): blocks [0,BB)           : per-batch counting sort -> tables
//             blocks [BB, BB+BB*64)   : edge weights in SORTED order
// r2 version, proven. (r3's fused spin-sync design regressed 2x: cross-block
// produce/consume spins are fragile under dispatch serialization -- reverted.)
// ---------------------------------------------------------------------------
__global__ __launch_bounds__(256) void prep_kernel(
    const float* __restrict__ embed,
    const int* __restrict__ sorted_index,
    const int* __restrict__ sorted_parent,
    const int* __restrict__ node_level,
    float* __restrict__ wsort,
    int*   __restrict__ giInv,
    int2*  __restrict__ cpl,
    int*   __restrict__ offs)
{
    int tid = threadIdx.x;
    if (blockIdx.x < BB) {
        int b = blockIdx.x;
        __shared__ int  pos_s[VV];            // 16 KB: i -> levelpos k
        __shared__ int4 cntv[NLEV * 64];      // 14 KB: [level][thread] counts/offsets
        __shared__ int  tot[NLEV];
        __shared__ int  offSh[NLEV + 1];
        int* cnt = (int*)cntv;
        const int* lev = node_level    + b * VV;
        const int* si  = sorted_index  + b * VV;
        const int* par = sorted_parent + b * VV;
        int lane = tid & 63;
        int w    = tid >> 6;

        // ---- load: thread owns elements i = 16*tid + m
        int dreg[16], sreg[16];
        #pragma unroll
        for (int t = 0; t < 4; ++t) {
            int4 dv = ((const int4*)lev)[tid * 4 + t];
            int4 sv = ((const int4*)si)[tid * 4 + t];
            #pragma unroll
            for (int j = 0; j < 4; ++j) {
                int d = (&dv.x)[j]; d = d < NLEV - 1 ? d : NLEV - 1;
                dreg[t * 4 + j] = d;
                sreg[t * 4 + j] = (&sv.x)[j];
            }
        }
        // ---- in-thread rank
        int rank[16];
        #pragma unroll
        for (int m = 0; m < 16; ++m) {
            int r = 0;
            #pragma unroll
            for (int m2 = 0; m2 < m; ++m2) r += (dreg[m2] == dreg[m]) ? 1 : 0;
            rank[m] = r;
        }
        // ---- per-thread per-level counts
        #pragma unroll
        for (int d = 0; d < NLEV; ++d) {
            int c = 0;
            #pragma unroll
            for (int m = 0; m < 16; ++m) c += (dreg[m] == d) ? 1 : 0;
            cnt[d * 256 + tid] = c;
        }
        __syncthreads();
        // ---- exclusive scan per level; wave w does levels w, w+4, ...
        for (int d = w; d < NLEV; d += 4) {
            int base = d * 64 + lane;
            int4 cv = cntv[base];
            int ls = cv.x + cv.y + cv.z + cv.w;
            int x = ls;
            #pragma unroll
            for (int off = 1; off < 64; off <<= 1) {
                int y = __shfl_up(x, off, 64);
                if (lane >= off) x += y;
            }
            int excl = x - ls;
            int4 ov;
            ov.x = excl;
            ov.y = excl + cv.x;
            ov.z = excl + cv.x + cv.y;
            ov.w = excl + cv.x + cv.y + cv.z;
            cntv[base] = ov;
            if (lane == 63) tot[d] = x;
        }
        __syncthreads();
        if (tid == 0) {
            int acc = 0;
            for (int d = 0; d < NLEV; ++d) { offSh[d] = acc; acc += tot[d]; }
            offSh[NLEV] = acc;
        }
        __syncthreads();
        if (tid <= NLEV) offs[b * 16 + tid] = offSh[tid];
        // ---- rank assignment
        int kreg[16];
        #pragma unroll
        for (int m = 0; m < 16; ++m) {
            int d = dreg[m];
            int k = offSh[d] + cnt[d * 256 + tid] + rank[m];
            kreg[m] = k;
            pos_s[16 * tid + m] = k;
            giInv[b * VV + sreg[m]] = k;
        }
        __syncthreads();
        // ---- emit cpl
        #pragma unroll
        for (int t = 0; t < 4; ++t) {
            int4 pv = ((const int4*)par)[tid * 4 + t];
            #pragma unroll
            for (int j = 0; j < 4; ++j) {
                int m = t * 4 + j;
                int p = (&pv.x)[j];
                cpl[b * VV + kreg[m]] = make_int2(pos_s[p], 16 * tid + m);
            }
        }
    } else {
        // weight: block = 64 nodes; wave w covers ce chunk [16w, 16w+16).
        __shared__ float part[4][64];
        int bb   = blockIdx.x - BB;
        int b    = bb >> 6;
        int n0   = (bb & 63) << 6;
        int lane = tid & 63;
        int w    = tid >> 6;
        int i    = n0 + lane;
        int vi = sorted_index[b * VV + i];
        int p  = sorted_parent[b * VV + i];
        int vp = sorted_index[b * VV + p];
        const float* eb = embed + (size_t)b * CE * VV;
        float acc = 0.f;
        #pragma unroll
        for (int r = 0; r < 16; ++r) {
            int ce = w * 16 + r;
            float d = eb[ce * VV + vi] - eb[ce * VV + vp];
            acc = fmaf(d, d, acc);
        }
        part[w][lane] = acc;
        __syncthreads();
        if (w == 0) {
            float d2 = part[0][lane] + part[1][lane] + part[2][lane] + part[3][lane];
            wsort[b * VV + i] = __expf(-d2);
        }
    }
}

// ---------------------------------------------------------------------------
// K2: tree filter, ONE channel per block. 512 blocks x 512 threads, 48 KB LDS
//     -> 2 blocks/CU co-resident (__launch_bounds__(512,4), VGPR<=128):
//     barrier/LDS-latency stalls of one block hide under the other's work,
//     and per-phase chain work drops 33% (2 chains/node vs 3). cw (immutable)
//     is register-prefetched across phase barriers; in the down-pass the
//     thread's own val[k]/nrm[k] (written only by this thread, this phase)
//     are prefetched too. val[cp] stays post-barrier (correctness).
//     cw packs {w_hi20, cp12}; val & nrm use the SAME truncated w so the
//     final division cancels most of the perturbation.
// ---------------------------------------------------------------------------
__global__ __launch_bounds__(512, 4) void tree1_kernel(
    const float* __restrict__ feat,
    const float* __restrict__ wsort,
    const int*  __restrict__ giInv,
    const int2* __restrict__ cpl,
    const int*  __restrict__ offs,
    float* __restrict__ out)
{
    __shared__ float val[VV];    // 16 KB  channel c by levelpos
    __shared__ float nrm[VV];    // 16 KB  normalizer
    __shared__ int   cw[VV];     // 16 KB  packed {w_hi20, cp12}
    __shared__ int   offS[16];
    int b   = blockIdx.x >> 7;   // 128 channels per batch
    int c   = blockIdx.x & 127;
    int tid = threadIdx.x;

    const int2*  cplB = cpl   + b * VV;
    const int*   ivB  = giInv + b * VV;
    const float* wsB  = wsort + b * VV;
    const float* f0   = feat + ((size_t)(b * CC + c)) * VV;

    if (tid < 16) offS[tid] = offs[b * 16 + tid];

    // stage + pack: coalesced int2 reads; w gather hits L1/L2 (16 KB/batch)
    #pragma unroll
    for (int t = 0; t < 8; ++t) {
        int k = tid + t * 512;
        int2 x = cplB[k];
        int wb = __float_as_int(wsB[x.y]);
        cw[k] = (wb & 0xFFFFF000) | x.x;
        nrm[k] = 1.f;
    }

    // init: coalesced float4/int4 reads, scattered b32 LDS writes; keep kk
    int4 kkR[2];
    #pragma unroll
    for (int t = 0; t < 2; ++t) {
        int idx = tid + t * 512;
        int4   kk = ((const int4*)ivB)[idx];
        float4 a  = ((const float4*)f0)[idx];
        kkR[t] = kk;
        val[kk.x] = a.x; val[kk.y] = a.y; val[kk.z] = a.z; val[kk.w] = a.w;
    }
    __syncthreads();

    // ---- upward: parents of level d are exactly level d-1 -> phase-safe
    //      atomics. cw prefetched one phase ahead (immutable).
    {
        int sN = offS[NLEV - 1], eN = offS[NLEV];
        int kN = sN + tid;
        int xN = (kN < eN) ? cw[kN] : 0;
        for (int d = NLEV - 1; d >= 1; --d) {
            int s = sN, e = eN, x0 = xN;
            sN = offS[d - 1]; eN = offS[d];
            kN = sN + tid;
            xN = (kN < eN) ? cw[kN] : 0;       // prefetch next phase's cw
            int k = s + tid;
            if (k < e) {
                float w = __int_as_float(x0 & 0xFFFFF000);
                int  cp = x0 & 0xFFF;
                lds_fadd(&val[cp], w * val[k]);
                lds_fadd(&nrm[cp], w * nrm[k]);
                for (k += 512; k < e; k += 512) {   // rare tail iterations
                    int x = cw[k];
                    w  = __int_as_float(x & 0xFFFFF000);
                    cp = x & 0xFFF;
                    lds_fadd(&val[cp], w * val[k]);
                    lds_fadd(&nrm[cp], w * nrm[k]);
                }
            }
            __syncthreads();
        }
    }

    // ---- downward: in place; parent (level d-1) final before level d reads
    //      it. Prefetch cw + own val/nrm (only this thread writes them, and
    //      only in their own phase); val[cp]/nrm[cp] read post-barrier.
    {
        int sN = offS[1], eN = offS[2];
        int kN = sN + tid;
        bool vN = kN < eN;
        int   xN = vN ? cw[kN]  : 0;
        float uN = vN ? val[kN] : 0.f;
        float nN = vN ? nrm[kN] : 0.f;
        for (int d = 1; d <= NLEV - 1; ++d) {
            int s = sN, e = eN, x0 = xN;
            float u0 = uN, n0 = nN;
            sN = offS[d + 1]; eN = offS[d + 2 <= NLEV ? d + 2 : NLEV];
            kN = sN + tid;
            bool v2 = (d + 1 <= NLEV - 1) && (kN < eN);
            xN = v2 ? cw[kN]  : 0;
            uN = v2 ? val[kN] : 0.f;
            nN = v2 ? nrm[kN] : 0.f;
            int k = s + tid;
            if (k < e) {
                float w = __int_as_float(x0 & 0xFFFFF000);
                int  cp = x0 & 0xFFF;
                val[k] = fmaf(w, fmaf(-w, u0, val[cp]), u0);
                nrm[k] = fmaf(w, fmaf(-w, n0, nrm[cp]), n0);
                for (k += 512; k < e; k += 512) {
                    int x = cw[k];
                    w  = __int_as_float(x & 0xFFFFF000);
                    cp = x & 0xFFF;
                    float u = val[k], n = nrm[k];
                    val[k] = fmaf(w, fmaf(-w, u, val[cp]), u);
                    nrm[k] = fmaf(w, fmaf(-w, n, nrm[cp]), n);
                }
            }
            __syncthreads();
        }
    }

    // epilogue: scattered b32 LDS reads, coalesced float4 stores
    float* o0 = out + ((size_t)(b * CC + c)) * VV;
    #pragma unroll
    for (int t = 0; t < 2; ++t) {
        int idx = tid + t * 512;
        int4 kk = kkR[t];
        float4 r0;
        r0.x = __fdividef(val[kk.x], nrm[kk.x]);
        r0.y = __fdividef(val[kk.y], nrm[kk.y]);
        r0.z = __fdividef(val[kk.z], nrm[kk.z]);
        r0.w = __fdividef(val[kk.w], nrm[kk.w]);
        ((float4*)o0)[idx] = r0;
    }
}

extern "C" void kernel_launch(void* const* d_in, const int* in_sizes, int n_in,
                              void* d_out, int out_size, void* d_ws, size_t ws_size,
                              hipStream_t stream) {
    const float* feat          = (const float*)d_in[0];
    const float* embed         = (const float*)d_in[1];
    const int*   sorted_index  = (const int*)d_in[2];
    const int*   sorted_parent = (const int*)d_in[3];
    const int*   node_level    = (const int*)d_in[4];
    float* out = (float*)d_out;

    char* ws = (char*)d_ws;
    const size_t A = (size_t)BB * VV * 4;     // 64 KB
    float* wsort = (float*)(ws);              // 64 KB
    int*   giInv = (int*)  (ws + A);          // 64 KB
    int2*  cpl   = (int2*) (ws + 2 * A);      // 128 KB
    int*   offs  = (int*)  (ws + 4 * A);      // 256 B

    prep_kernel<<<BB + BB * 64, 256, 0, stream>>>(
        embed, sorted_index, sorted_parent, node_level, wsort, giInv, cpl, offs);

    tree1_kernel<<<BB * CC, 512, 0, stream>>>(
        feat, wsort, giInv, cpl, offs, out);
}

// Round 5
// 104.777 us; speedup vs baseline: 1.9595x; 1.0601x over previous
//
#include <hip/hip_runtime.h>

// Problem constants (match reference setup_inputs).
#define BB 4
#define CC 128
#define CE 64
#define VV 4096
#define NLEV 14   // MAX_LEVELS

// Workspace (r2 layout):
//   wsort [BB*VV] float : edge weight of node at SORTED position i
//   giInv [BB*VV] int   : levelpos of pixel v
//   cpl   [BB*VV] int2  : {cp (levelpos of parent), sorted idx i} at levelpos k
//   offs  [BB*16] int   : level start offsets

__device__ __forceinline__ void lds_fadd(float* p, float v) {
    unsafeAtomicAdd(p, v);   // ds_add_f32 on gfx950 LDS
}

// ---------------------------------------------------------------------------
// K1 (fused): blocks [0,BB)           : per-batch counting sort -> tables
//             blocks [BB, BB+BB*64)   : edge weights in SORTED order
// r2 version, byte-identical (proven 103.3us component).
// ---------------------------------------------------------------------------
__global__ __launch_bounds__(256) void prep_kernel(
    const float* __restrict__ embed,
    const int* __restrict__ sorted_index,
    const int* __restrict__ sorted_parent,
    const int* __restrict__ node_level,
    float* __restrict__ wsort,
    int*   __restrict__ giInv,
    int2*  __restrict__ cpl,
    int*   __restrict__ offs)
{
    int tid = threadIdx.x;
    if (blockIdx.x < BB) {
        int b = blockIdx.x;
        __shared__ int  pos_s[VV];            // 16 KB: i -> levelpos k
        __shared__ int4 cntv[NLEV * 64];      // 14 KB: [level][thread] counts/offsets
        __shared__ int  tot[NLEV];
        __shared__ int  offSh[NLEV + 1];
        int* cnt = (int*)cntv;
        const int* lev = node_level    + b * VV;
        const int* si  = sorted_index  + b * VV;
        const int* par = sorted_parent + b * VV;
        int lane = tid & 63;
        int w    = tid >> 6;

        // ---- load: thread owns elements i = 16*tid + m
        int dreg[16], sreg[16];
        #pragma unroll
        for (int t = 0; t < 4; ++t) {
            int4 dv = ((const int4*)lev)[tid * 4 + t];
            int4 sv = ((const int4*)si)[tid * 4 + t];
            #pragma unroll
            for (int j = 0; j < 4; ++j) {
                int d = (&dv.x)[j]; d = d < NLEV - 1 ? d : NLEV - 1;
                dreg[t * 4 + j] = d;
                sreg[t * 4 + j] = (&sv.x)[j];
            }
        }
        // ---- in-thread rank
        int rank[16];
        #pragma unroll
        for (int m = 0; m < 16; ++m) {
            int r = 0;
            #pragma unroll
            for (int m2 = 0; m2 < m; ++m2) r += (dreg[m2] == dreg[m]) ? 1 : 0;
            rank[m] = r;
        }
        // ---- per-thread per-level counts
        #pragma unroll
        for (int d = 0; d < NLEV; ++d) {
            int c = 0;
            #pragma unroll
            for (int m = 0; m < 16; ++m) c += (dreg[m] == d) ? 1 : 0;
            cnt[d * 256 + tid] = c;
        }
        __syncthreads();
        // ---- exclusive scan per level; wave w does levels w, w+4, ...
        for (int d = w; d < NLEV; d += 4) {
            int base = d * 64 + lane;
            int4 cv = cntv[base];
            int ls = cv.x + cv.y + cv.z + cv.w;
            int x = ls;
            #pragma unroll
            for (int off = 1; off < 64; off <<= 1) {
                int y = __shfl_up(x, off, 64);
                if (lane >= off) x += y;
            }
            int excl = x - ls;
            int4 ov;
            ov.x = excl;
            ov.y = excl + cv.x;
            ov.z = excl + cv.x + cv.y;
            ov.w = excl + cv.x + cv.y + cv.z;
            cntv[base] = ov;
            if (lane == 63) tot[d] = x;
        }
        __syncthreads();
        if (tid == 0) {
            int acc = 0;
            for (int d = 0; d < NLEV; ++d) { offSh[d] = acc; acc += tot[d]; }
            offSh[NLEV] = acc;
        }
        __syncthreads();
        if (tid <= NLEV) offs[b * 16 + tid] = offSh[tid];
        // ---- rank assignment
        int kreg[16];
        #pragma unroll
        for (int m = 0; m < 16; ++m) {
            int d = dreg[m];
            int k = offSh[d] + cnt[d * 256 + tid] + rank[m];
            kreg[m] = k;
            pos_s[16 * tid + m] = k;
            giInv[b * VV + sreg[m]] = k;
        }
        __syncthreads();
        // ---- emit cpl
        #pragma unroll
        for (int t = 0; t < 4; ++t) {
            int4 pv = ((const int4*)par)[tid * 4 + t];
            #pragma unroll
            for (int j = 0; j < 4; ++j) {
                int m = t * 4 + j;
                int p = (&pv.x)[j];
                cpl[b * VV + kreg[m]] = make_int2(pos_s[p], 16 * tid + m);
            }
        }
    } else {
        // weight: block = 64 nodes; wave w covers ce chunk [16w, 16w+16).
        __shared__ float part[4][64];
        int bb   = blockIdx.x - BB;
        int b    = bb >> 6;
        int n0   = (bb & 63) << 6;
        int lane = tid & 63;
        int w    = tid >> 6;
        int i    = n0 + lane;
        int vi = sorted_index[b * VV + i];
        int p  = sorted_parent[b * VV + i];
        int vp = sorted_index[b * VV + p];
        const float* eb = embed + (size_t)b * CE * VV;
        float acc = 0.f;
        #pragma unroll
        for (int r = 0; r < 16; ++r) {
            int ce = w * 16 + r;
            float d = eb[ce * VV + vi] - eb[ce * VV + vp];
            acc = fmaf(d, d, acc);
        }
        part[w][lane] = acc;
        __syncthreads();
        if (w == 0) {
            float d2 = part[0][lane] + part[1][lane] + part[2][lane] + part[3][lane];
            wsort[b * VV + i] = __expf(-d2);
        }
    }
}

// ---------------------------------------------------------------------------
// K2: tree filter, TWO channels per block (r2 shape: 256 blocks, 64 KB LDS,
//     minimizes per-block serial time at minimal duplicated work -- r4's
//     1-ch x512 grid regressed: +33% chain work, +2x staging).
// r5 changes, all work-neutral:
//   - 1024 threads: peak levels (~700-1000 nodes) do 1 iteration instead of
//     2 -> halves serial depth of fat phases; staging trip counts halve.
//   - cross-barrier prefetch: up-pass prefetches cw (immutable) one phase
//     ahead; down-pass prefetches cw + own val/nrm (next level: written by
//     nobody during current phase; clamp target is level 0, never written
//     in the down-pass). Only [cp] gathers stay post-barrier.
//   - nrm init folded into the coalesced stage loop.
// cw packs {w_hi20, cp12}; val & nrm use the SAME truncated w so the final
// division cancels most of the perturbation.
// ---------------------------------------------------------------------------
__global__ __launch_bounds__(1024) void tree2_kernel(
    const float* __restrict__ feat,
    const float* __restrict__ wsort,
    const int*  __restrict__ giInv,
    const int2* __restrict__ cpl,
    const int*  __restrict__ offs,
    float* __restrict__ out)
{
    __shared__ float val0[VV];   // 16 KB  channel c0 by levelpos
    __shared__ float val1[VV];   // 16 KB  channel c0+1
    __shared__ float nrm[VV];    // 16 KB  shared normalizer
    __shared__ int   cw[VV];     // 16 KB  packed {w_hi20, cp12}
    __shared__ int   offS[16];
    int b   = blockIdx.x >> 6;   // 64 channel-pairs per batch
    int c0  = (blockIdx.x & 63) << 1;
    int tid = threadIdx.x;

    const int2*  cplB = cpl   + b * VV;
    const int*   ivB  = giInv + b * VV;
    const float* wsB  = wsort + b * VV;
    const float* f0   = feat + ((size_t)(b * CC + c0)) * VV;
    const float* f1   = f0 + VV;

    if (tid < 16) offS[tid] = offs[b * 16 + tid];

    // stage + pack + nrm init: coalesced int2 reads; w gather hits L1/L2
    #pragma unroll
    for (int t = 0; t < 4; ++t) {
        int k = tid + t * 1024;
        int2 x = cplB[k];
        int wb = __float_as_int(wsB[x.y]);
        cw[k] = (wb & 0xFFFFF000) | x.x;
        nrm[k] = 1.f;
    }

    // init: coalesced float4/int4 reads, scattered b32 LDS writes; keep kk
    int4 kk = ((const int4*)ivB)[tid];
    {
        float4 a  = ((const float4*)f0)[tid];
        float4 bq = ((const float4*)f1)[tid];
        val0[kk.x] = a.x;  val0[kk.y] = a.y;  val0[kk.z] = a.z;  val0[kk.w] = a.w;
        val1[kk.x] = bq.x; val1[kk.y] = bq.y; val1[kk.z] = bq.z; val1[kk.w] = bq.w;
    }
    __syncthreads();

    // ---- upward: parents of level d are exactly level d-1 -> phase-safe
    //      atomics. cw prefetched one phase ahead (immutable -> race-free).
    {
        int x0;
        { int kP = offS[NLEV - 1] + tid;
          x0 = cw[kP < offS[NLEV] ? kP : 0]; }       // lvl 13 usually empty
        for (int d = NLEV - 1; d >= 1; --d) {
            int s = offS[d], e = offS[d + 1];
            int xN = 0;
            if (d > 1) {
                int kP = offS[d - 1] + tid;
                xN = cw[kP < offS[d] ? kP : 0];
            }
            if (s < e) {                              // offS uniform -> safe
                int k = s + tid;
                if (k < e) {
                    float w = __int_as_float(x0 & 0xFFFFF000);
                    int  cp = x0 & 0xFFF;
                    lds_fadd(&val0[cp], w * val0[k]);
                    lds_fadd(&val1[cp], w * val1[k]);
                    lds_fadd(&nrm[cp],  w * nrm[k]);
                    for (k += 1024; k < e; k += 1024) {   // rare tail
                        int x = cw[k];
                        w  = __int_as_float(x & 0xFFFFF000);
                        cp = x & 0xFFF;
                        lds_fadd(&val0[cp], w * val0[k]);
                        lds_fadd(&val1[cp], w * val1[k]);
                        lds_fadd(&nrm[cp],  w * nrm[k]);
                    }
                }
                __syncthreads();
            }
            x0 = xN;
        }
    }

    // ---- downward: in place; parent (level d-1) final before level d reads
    //      it. Prefetch next level's cw + own val/nrm during current phase
    //      (disjoint: phase d writes only level d; clamp target is level 0,
    //      never written in the down-pass).
    {
        int xd; float u0N, u1N, nN;
        { int kP = offS[1] + tid;
          int kc = kP < offS[2] ? kP : 0;
          xd = cw[kc]; u0N = val0[kc]; u1N = val1[kc]; nN = nrm[kc]; }
        for (int d = 1; d <= NLEV - 1; ++d) {
            int s = offS[d], e = offS[d + 1];
            int x0 = xd; float u0 = u0N, u1 = u1N, n0 = nN;
            if (d < NLEV - 1) {
                int kP = offS[d + 1] + tid;
                int kc = kP < offS[d + 2] ? kP : 0;
                xd = cw[kc]; u0N = val0[kc]; u1N = val1[kc]; nN = nrm[kc];
            }
            if (s < e) {
                int k = s + tid;
                if (k < e) {
                    float w = __int_as_float(x0 & 0xFFFFF000);
                    int  cp = x0 & 0xFFF;
                    val0[k] = fmaf(w, fmaf(-w, u0, val0[cp]), u0);
                    val1[k] = fmaf(w, fmaf(-w, u1, val1[cp]), u1);
                    nrm[k]  = fmaf(w, fmaf(-w, n0, nrm[cp]),  n0);
                    for (k += 1024; k < e; k += 1024) {   // rare tail
                        int x = cw[k];
                        w  = __int_as_float(x & 0xFFFFF000);
                        cp = x & 0xFFF;
                        float uu0 = val0[k], uu1 = val1[k], un = nrm[k];
                        val0[k] = fmaf(w, fmaf(-w, uu0, val0[cp]), uu0);
                        val1[k] = fmaf(w, fmaf(-w, uu1, val1[cp]), uu1);
                        nrm[k]  = fmaf(w, fmaf(-w, un,  nrm[cp]),  un);
                    }
                }
                __syncthreads();
            }
        }
    }

    // epilogue: scattered b32 LDS reads, coalesced float4 stores, 2 channels
    float* o0 = out + ((size_t)(b * CC + c0)) * VV;
    float* o1 = o0 + VV;
    {
        float i0 = __fdividef(1.f, nrm[kk.x]);
        float i1 = __fdividef(1.f, nrm[kk.y]);
        float i2 = __fdividef(1.f, nrm[kk.z]);
        float i3 = __fdividef(1.f, nrm[kk.w]);
        float4 r0, r1;
        r0.x = val0[kk.x] * i0; r0.y = val0[kk.y] * i1;
        r0.z = val0[kk.z] * i2; r0.w = val0[kk.w] * i3;
        r1.x = val1[kk.x] * i0; r1.y = val1[kk.y] * i1;
        r1.z = val1[kk.z] * i2; r1.w = val1[kk.w] * i3;
        ((float4*)o0)[tid] = r0;
        ((float4*)o1)[tid] = r1;
    }
}

extern "C" void kernel_launch(void* const* d_in, const int* in_sizes, int n_in,
                              void* d_out, int out_size, void* d_ws, size_t ws_size,
                              hipStream_t stream) {
    const float* feat          = (const float*)d_in[0];
    const float* embed         = (const float*)d_in[1];
    const int*   sorted_index  = (const int*)d_in[2];
    const int*   sorted_parent = (const int*)d_in[3];
    const int*   node_level    = (const int*)d_in[4];
    float* out = (float*)d_out;

    char* ws = (char*)d_ws;
    const size_t A = (size_t)BB * VV * 4;     // 64 KB
    float* wsort = (float*)(ws);              // 64 KB
    int*   giInv = (int*)  (ws + A);          // 64 KB
    int2*  cpl   = (int2*) (ws + 2 * A);      // 128 KB
    int*   offs  = (int*)  (ws + 4 * A);      // 256 B

    prep_kernel<<<BB + BB * 64, 256, 0, stream>>>(
        embed, sorted_index, sorted_parent, node_level, wsort, giInv, cpl, offs);

    tree2_kernel<<<BB * CC / 2, 1024, 0, stream>>>(
        feat, wsort, giInv, cpl, offs, out);
}

// Round 6
// 104.691 us; speedup vs baseline: 1.9612x; 1.0008x over previous
//
#include <hip/hip_runtime.h>

// Problem constants (match reference setup_inputs).
#define BB 4
#define CC 128
#define CE 64
#define VV 4096
#define NLEV 14   // MAX_LEVELS

// Workspace:
//   wsort [BB*VV] float : edge weight of node at SORTED position i
//   giInv [BB*VV] int   : levelpos of pixel v
//   cpl   [BB*VV] int2  : {cp (levelpos of parent), sorted idx i} at levelpos k
//   offs  [BB*16] int   : level start offsets

__device__ __forceinline__ void lds_fadd(float* p, float v) {
    unsafeAtomicAdd(p, v);   // ds_add_f32 on gfx950 LDS
}

// ---------------------------------------------------------------------------
// K1 (fused): blocks [0,BB)           : per-batch counting sort -> tables
//             blocks [BB, BB+BB*64)   : edge weights in SORTED order
//
// Sort: register counts + wave-scan + direct rank (r2, proven). Zero atomics,
// zero ballots. Within-level order is deterministic pixel order -- semantics-
// preserving (up-pass is an order-free sum, down-pass per-node).
// Session history: r1 ballot-rank +13us (dependent ballot->atomic->shfl
// chain); r3 fused spin-sync +102us (spins fragile under dispatch
// serialization); r4 1-ch tree split +7.8us (+33% chain work); r5 1024-thr
// prefetch +1.5us (phase cost is post-barrier gather+atomic+barrier, not
// prefetchable). This file is the measured-best r2 configuration.
// ---------------------------------------------------------------------------
__global__ __launch_bounds__(256) void prep_kernel(
    const float* __restrict__ embed,
    const int* __restrict__ sorted_index,
    const int* __restrict__ sorted_parent,
    const int* __restrict__ node_level,
    float* __restrict__ wsort,
    int*   __restrict__ giInv,
    int2*  __restrict__ cpl,
    int*   __restrict__ offs)
{
    int tid = threadIdx.x;
    if (blockIdx.x < BB) {
        int b = blockIdx.x;
        __shared__ int  pos_s[VV];            // 16 KB: i -> levelpos k
        __shared__ int4 cntv[NLEV * 64];      // 14 KB: [level][thread] counts/offsets
        __shared__ int  tot[NLEV];
        __shared__ int  offSh[NLEV + 1];
        int* cnt = (int*)cntv;
        const int* lev = node_level    + b * VV;
        const int* si  = sorted_index  + b * VV;
        const int* par = sorted_parent + b * VV;
        int lane = tid & 63;
        int w    = tid >> 6;

        // ---- load: thread owns elements i = 16*tid + m
        int dreg[16], sreg[16];
        #pragma unroll
        for (int t = 0; t < 4; ++t) {
            int4 dv = ((const int4*)lev)[tid * 4 + t];
            int4 sv = ((const int4*)si)[tid * 4 + t];
            #pragma unroll
            for (int j = 0; j < 4; ++j) {
                int d = (&dv.x)[j]; d = d < NLEV - 1 ? d : NLEV - 1;
                dreg[t * 4 + j] = d;
                sreg[t * 4 + j] = (&sv.x)[j];
            }
        }
        // ---- in-thread rank
        int rank[16];
        #pragma unroll
        for (int m = 0; m < 16; ++m) {
            int r = 0;
            #pragma unroll
            for (int m2 = 0; m2 < m; ++m2) r += (dreg[m2] == dreg[m]) ? 1 : 0;
            rank[m] = r;
        }
        // ---- per-thread per-level counts
        #pragma unroll
        for (int d = 0; d < NLEV; ++d) {
            int c = 0;
            #pragma unroll
            for (int m = 0; m < 16; ++m) c += (dreg[m] == d) ? 1 : 0;
            cnt[d * 256 + tid] = c;
        }
        __syncthreads();
        // ---- exclusive scan over threads, per level; wave w does levels w,w+4,...
        for (int d = w; d < NLEV; d += 4) {
            int base = d * 64 + lane;          // int4 granularity
            int4 cv = cntv[base];
            int ls = cv.x + cv.y + cv.z + cv.w;
            int x = ls;
            #pragma unroll
            for (int off = 1; off < 64; off <<= 1) {
                int y = __shfl_up(x, off, 64);
                if (lane >= off) x += y;
            }
            int excl = x - ls;
            int4 ov;
            ov.x = excl;
            ov.y = excl + cv.x;
            ov.z = excl + cv.x + cv.y;
            ov.w = excl + cv.x + cv.y + cv.z;
            cntv[base] = ov;
            if (lane == 63) tot[d] = x;
        }
        __syncthreads();
        if (tid == 0) {
            int acc = 0;
            for (int d = 0; d < NLEV; ++d) { offSh[d] = acc; acc += tot[d]; }
            offSh[NLEV] = acc;
        }
        __syncthreads();
        if (tid <= NLEV) offs[b * 16 + tid] = offSh[tid];

        // ---- rank assignment: pure LDS reads, no RMW
        int kreg[16];
        #pragma unroll
        for (int m = 0; m < 16; ++m) {
            int d = dreg[m];
            int k = offSh[d] + cnt[d * 256 + tid] + rank[m];
            kreg[m] = k;
            pos_s[16 * tid + m] = k;
            giInv[b * VV + sreg[m]] = k;
        }
        __syncthreads();

        // ---- emit cpl from the i-side (pos_s[p] is the only LDS gather)
        #pragma unroll
        for (int t = 0; t < 4; ++t) {
            int4 pv = ((const int4*)par)[tid * 4 + t];
            #pragma unroll
            for (int j = 0; j < 4; ++j) {
                int m = t * 4 + j;
                int p = (&pv.x)[j];
                cpl[b * VV + kreg[m]] = make_int2(pos_s[p], 16 * tid + m);
            }
        }
    } else {
        // weight: block = 64 nodes; wave w covers ce chunk [16w, 16w+16).
        __shared__ float part[4][64];
        int bb   = blockIdx.x - BB;
        int b    = bb >> 6;
        int n0   = (bb & 63) << 6;
        int lane = tid & 63;
        int w    = tid >> 6;
        int i    = n0 + lane;
        int vi = sorted_index[b * VV + i];
        int p  = sorted_parent[b * VV + i];
        int vp = sorted_index[b * VV + p];
        const float* eb = embed + (size_t)b * CE * VV;
        float acc = 0.f;
        #pragma unroll
        for (int r = 0; r < 16; ++r) {
            int ce = w * 16 + r;
            float d = eb[ce * VV + vi] - eb[ce * VV + vp];
            acc = fmaf(d, d, acc);
        }
        part[w][lane] = acc;
        __syncthreads();
        if (w == 0) {
            float d2 = part[0][lane] + part[1][lane] + part[2][lane] + part[3][lane];
            wsort[b * VV + i] = __expf(-d2);
        }
    }
}

// ---------------------------------------------------------------------------
// K2: tree filter, TWO channels per block + shared nrm chain. 256 blocks,
//     512 threads (8 waves/CU), 64 KB LDS. vs one-channel blocks: LDS atomic
//     total -25%, cw/giInv staging traffic -50%, nrm chains 128->64 per batch.
//     cw packs {w_hi20, cp12}; val & nrm use the SAME truncated w so the
//     final division cancels most of the perturbation.
// ---------------------------------------------------------------------------
__global__ __launch_bounds__(512) void tree2_kernel(
    const float* __restrict__ feat,
    const float* __restrict__ wsort,
    const int*  __restrict__ giInv,
    const int2* __restrict__ cpl,
    const int*  __restrict__ offs,
    float* __restrict__ out)
{
    __shared__ float val0[VV];   // 16 KB  channel c0 by levelpos
    __shared__ float val1[VV];   // 16 KB  channel c0+1
    __shared__ float nrm[VV];    // 16 KB  shared normalizer
    __shared__ int   cw[VV];     // 16 KB  packed {w_hi20, cp12}
    __shared__ int   offS[16];
    int b   = blockIdx.x >> 6;   // 64 channel-pairs per batch
    int c0  = (blockIdx.x & 63) << 1;
    int tid = threadIdx.x;

    const int2*  cplB = cpl   + b * VV;
    const int*   ivB  = giInv + b * VV;
    const float* wsB  = wsort + b * VV;
    const float* f0   = feat + ((size_t)(b * CC + c0)) * VV;
    const float* f1   = f0 + VV;

    if (tid < 16) offS[tid] = offs[b * 16 + tid];

    // stage + pack: coalesced int2 reads; w gather hits L1/L2 (16 KB/batch)
    #pragma unroll
    for (int t = 0; t < 8; ++t) {
        int k = tid + t * 512;
        int2 x = cplB[k];
        int wb = __float_as_int(wsB[x.y]);
        cw[k] = (wb & 0xFFFFF000) | x.x;
    }

    // init: coalesced float4/int4 reads, scattered b32 LDS writes; keep kk
    int4 kkR[2];
    #pragma unroll
    for (int t = 0; t < 2; ++t) {
        int idx = tid + t * 512;
        int4   kk = ((const int4*)ivB)[idx];
        float4 a  = ((const float4*)f0)[idx];
        float4 bq = ((const float4*)f1)[idx];
        kkR[t] = kk;
        val0[kk.x] = a.x;  val0[kk.y] = a.y;  val0[kk.z] = a.z;  val0[kk.w] = a.w;
        val1[kk.x] = bq.x; val1[kk.y] = bq.y; val1[kk.z] = bq.z; val1[kk.w] = bq.w;
        nrm[kk.x] = 1.f;   nrm[kk.y] = 1.f;   nrm[kk.z] = 1.f;   nrm[kk.w] = 1.f;
    }
    __syncthreads();

    // upward: parents of level d are exactly level d-1 -> phase-safe atomics
    for (int d = NLEV - 1; d >= 1; --d) {
        int s = offS[d], e = offS[d + 1];
        if (s == e) continue;                 // offS uniform -> safe skip
        for (int k = s + tid; k < e; k += 512) {
            int x = cw[k];
            float w = __int_as_float(x & 0xFFFFF000);
            int  cp = x & 0xFFF;
            lds_fadd(&val0[cp], w * val0[k]);
            lds_fadd(&val1[cp], w * val1[k]);
            lds_fadd(&nrm[cp],  w * nrm[k]);
        }
        __syncthreads();
    }

    // downward: in place; parent (level d-1) final before level d reads it
    for (int d = 1; d <= NLEV - 1; ++d) {
        int s = offS[d], e = offS[d + 1];
        if (s == e) continue;
        for (int k = s + tid; k < e; k += 512) {
            int x = cw[k];
            float w = __int_as_float(x & 0xFFFFF000);
            int  cp = x & 0xFFF;
            float u0 = val0[k], u1 = val1[k], un = nrm[k];
            val0[k] = fmaf(w, fmaf(-w, u0, val0[cp]), u0);
            val1[k] = fmaf(w, fmaf(-w, u1, val1[cp]), u1);
            nrm[k]  = fmaf(w, fmaf(-w, un, nrm[cp]),  un);
        }
        __syncthreads();
    }

    // epilogue: scattered b32 LDS reads, coalesced float4 stores, 2 channels
    float* o0 = out + ((size_t)(b * CC + c0)) * VV;
    float* o1 = o0 + VV;
    #pragma unroll
    for (int t = 0; t < 2; ++t) {
        int idx = tid + t * 512;
        int4 kk = kkR[t];
        float i0 = __fdividef(1.f, nrm[kk.x]);
        float i1 = __fdividef(1.f, nrm[kk.y]);
        float i2 = __fdividef(1.f, nrm[kk.z]);
        float i3 = __fdividef(1.f, nrm[kk.w]);
        float4 r0, r1;
        r0.x = val0[kk.x] * i0; r0.y = val0[kk.y] * i1;
        r0.z = val0[kk.z] * i2; r0.w = val0[kk.w] * i3;
        r1.x = val1[kk.x] * i0; r1.y = val1[kk.y] * i1;
        r1.z = val1[kk.z] * i2; r1.w = val1[kk.w] * i3;
        ((float4*)o0)[idx] = r0;
        ((float4*)o1)[idx] = r1;
    }
}

extern "C" void kernel_launch(void* const* d_in, const int* in_sizes, int n_in,
                              void* d_out, int out_size, void* d_ws, size_t ws_size,
                              hipStream_t stream) {
    const float* feat          = (const float*)d_in[0];
    const float* embed         = (const float*)d_in[1];
    const int*   sorted_index  = (const int*)d_in[2];
    const int*   sorted_parent = (const int*)d_in[3];
    const int*   node_level    = (const int*)d_in[4];
    float* out = (float*)d_out;

    char* ws = (char*)d_ws;
    const size_t A = (size_t)BB * VV * 4;     // 64 KB
    float* wsort = (float*)(ws);              // 64 KB
    int*   giInv = (int*)  (ws + A);          // 64 KB
    int2*  cpl   = (int2*) (ws + 2 * A);      // 128 KB
    int*   offs  = (int*)  (ws + 4 * A);      // 256 B

    prep_kernel<<<BB + BB * 64, 256, 0, stream>>>(
        embed, sorted_index, sorted_parent, node_level, wsort, giInv, cpl, offs);

    tree2_kernel<<<BB * CC / 2, 512, 0, stream>>>(
        feat, wsort, giInv, cpl, offs, out);
}